// Round 3
// baseline (565.025 us; speedup 1.0000x reference)
//
#include <hip/hip_runtime.h>
#include <math.h>

#define WT_LEN 512
#define N_WT 20
#define B_ 16
#define T_ 262144           // 2^18 per row
#define TOTAL (B_ * T_)     // 4194304
#define CHUNK 8192          // level-0 elems per block (one level-13 unit)
#define NCHR 32             // chunks per row
#define NCH  512            // total chunks
#define DTHREADS 1024

// inc = (pitch / 44100) * 512 ; f32 division is correctly rounded (verified:
// f32-div and f64-div-then-round gave bit-identical results in R1/R2).
__device__ __forceinline__ float to_inc1(float x) {
    return (x / 44100.0f) * 512.0f;
}
__device__ __forceinline__ float4 to_inc4(float4 p) {
    float4 r;
    r.x = to_inc1(p.x); r.y = to_inc1(p.y);
    r.z = to_inc1(p.z); r.w = to_inc1(p.w);
    return r;
}

// ---------------------------------------------------------------------------
// U: per-chunk exact adjacent-pair tree reduction -> A13[chunk].
// Structure MUST be A_k[i] = A_{k-1}[2i] + A_{k-1}[2i+1] at every level.
// Optionally stores the increments to global so D can skip the divisions.
// ---------------------------------------------------------------------------
template <bool STORE_INC>
__global__ __launch_bounds__(DTHREADS) void up_kernel(
        const float* __restrict__ pitch, float* __restrict__ A13,
        float* __restrict__ incbuf) {
    __shared__ float red[2048];
    const int t = threadIdx.x;
    const size_t g0 = (size_t)blockIdx.x * CHUNK;

    const float4* p4 = (const float4*)(pitch + g0);
    float4 v0 = to_inc4(p4[2 * t]);
    float4 v1 = to_inc4(p4[2 * t + 1]);
    if (STORE_INC) {
        float4* q4 = (float4*)(incbuf + g0);
        q4[2 * t] = v0; q4[2 * t + 1] = v1;
    }
    // exact balanced tree over the thread's 8 contiguous elems (levels 1..3)
    float t0 = v0.x + v0.y, t1 = v0.z + v0.w;
    float t2 = v1.x + v1.y, t3 = v1.z + v1.w;
    red[t] = (t0 + t1) + (t2 + t3);        // A_3[global]
    __syncthreads();
    // levels 4..13 in distinct LDS slices (no in-place races)
    int off_prev = 0, off = 1024;
    for (int sz = 512; sz >= 1; sz >>= 1) {
        if (t < sz) red[off + t] = red[off_prev + 2 * t] + red[off_prev + 2 * t + 1];
        __syncthreads();
        off_prev = off; off += sz;
    }
    if (t == 0) A13[blockIdx.x] = red[2046];
}

// ---------------------------------------------------------------------------
// M: per-row exact odd-even-recursion scan of the 32 chunk totals -> S13.
// Also computes per-row x0 = increment[row][0].
// ---------------------------------------------------------------------------
__global__ void mid_kernel(const float* __restrict__ A13,
                           const float* __restrict__ pitch,
                           float* __restrict__ S13, float* __restrict__ X0) {
    int r = threadIdx.x;
    if (r >= B_) return;
    float l0[32], l1[16], l2[8], l3[4], l4[2], l5;
    for (int i = 0; i < 32; ++i) l0[i] = A13[r * 32 + i];
    for (int i = 0; i < 16; ++i) l1[i] = l0[2 * i] + l0[2 * i + 1];
    for (int i = 0; i < 8;  ++i) l2[i] = l1[2 * i] + l1[2 * i + 1];
    for (int i = 0; i < 4;  ++i) l3[i] = l2[2 * i] + l2[2 * i + 1];
    for (int i = 0; i < 2;  ++i) l4[i] = l3[2 * i] + l3[2 * i + 1];
    l5 = l4[0] + l4[1];

    float s4[2], s3[4], s2[8], s1[16], s0[32];
    s4[0] = l4[0]; s4[1] = l5;
    s3[0] = l3[0];
    for (int i = 0; i < 2; ++i) {
        s3[2 * i + 1] = s4[i];
        if (2 * i + 2 < 4) s3[2 * i + 2] = s4[i] + l3[2 * i + 2];
    }
    s2[0] = l2[0];
    for (int i = 0; i < 4; ++i) {
        s2[2 * i + 1] = s3[i];
        if (2 * i + 2 < 8) s2[2 * i + 2] = s3[i] + l2[2 * i + 2];
    }
    s1[0] = l1[0];
    for (int i = 0; i < 8; ++i) {
        s1[2 * i + 1] = s2[i];
        if (2 * i + 2 < 16) s1[2 * i + 2] = s2[i] + l1[2 * i + 2];
    }
    s0[0] = l0[0];
    for (int i = 0; i < 16; ++i) {
        s0[2 * i + 1] = s1[i];
        if (2 * i + 2 < 32) s0[2 * i + 2] = s1[i] + l0[2 * i + 2];
    }
    for (int i = 0; i < 32; ++i) S13[r * 32 + i] = s0[i];
    X0[r] = to_inc1(pitch[(size_t)r * T_]);
}

// ---------------------------------------------------------------------------
// D: per chunk — rebuild levels 0..12 in LDS (exact up-sweep), then exact
// in-place down-sweep seeded by P = S13[chunk-1] (chunk prefix; the copy rule
// S_k[2i+1] = S_{k+1}[i] makes this the only external value needed) and
// S13[chunk] (the odd seed at level 12). Writes S (final scan) to sout.
// ---------------------------------------------------------------------------
__constant__ int OFF[14] = {0, 8192, 12288, 14336, 15360, 15872, 16128,
                            16256, 16320, 16352, 16368, 16376, 16380, 16382};

template <bool FROM_INC>
__global__ __launch_bounds__(DTHREADS) void down_kernel(
        const float* __restrict__ src,   // incbuf (FROM_INC) or pitch
        const float* __restrict__ S13,
        float* __restrict__ sout) {
    __shared__ float a[16384];
    const int t = threadIdx.x;
    const size_t g0 = (size_t)blockIdx.x * CHUNK;

    const float4* p4 = (const float4*)(src + g0);
    float4 v0 = p4[2 * t], v1 = p4[2 * t + 1];
    if (!FROM_INC) { v0 = to_inc4(v0); v1 = to_inc4(v1); }
    ((float4*)a)[2 * t] = v0;
    ((float4*)a)[2 * t + 1] = v1;
    __syncthreads();

    // up-sweep: A_k[i] = A_{k-1}[2i] + A_{k-1}[2i+1], k = 1..12
    for (int k = 1; k <= 12; ++k) {
        int m = CHUNK >> k;
        int bp = OFF[k - 1], b = OFF[k];
        for (int i = t; i < m; i += DTHREADS)
            a[b + i] = a[bp + 2 * i] + a[bp + 2 * i + 1];
        __syncthreads();
    }

    const float P = (blockIdx.x & (NCHR - 1)) ? S13[blockIdx.x - 1] : 0.0f;
    const float T13 = S13[blockIdx.x];

    // down-sweep, in place over each level slice
    if (t == 0) {
        a[OFF[12]]     = P + a[OFF[12]];   // s12[0]
        a[OFF[12] + 1] = T13;              // s12[1] == S_13[chunk] (copy rule)
    }
    __syncthreads();
    for (int k = 11; k >= 0; --k) {
        int m = CHUNK >> k, half = m >> 1;
        int b = OFF[k], bn = OFF[k + 1];
        for (int i = t; i < half; i += DTHREADS) {
            float sn = a[bn + i];                  // s_{k+1}[i], finalized
            int j = 2 * i + 2;
            float av = (j < m) ? a[b + j] : 0.0f;  // raw A_k, read pre-write
            a[b + 2 * i + 1] = sn;                 // s_k[2i+1] = s_{k+1}[i]
            if (j < m) a[b + j] = sn + av;         // s_k[2i+2]
        }
        if (t == 0) a[b] = P + a[b];               // s_k[0] (P=0 row-start: exact)
        __syncthreads();
    }

    float4* q4 = (float4*)(sout + g0);
    q4[2 * t]     = ((float4*)a)[2 * t];
    q4[2 * t + 1] = ((float4*)a)[2 * t + 1];
}

// ---------------------------------------------------------------------------
// mix: index -> gather -> mix; in-place on io (= d_out holding S).
// ---------------------------------------------------------------------------
__global__ __launch_bounds__(256) void mix_kernel(
        float* io, const float* __restrict__ X0,
        const float* __restrict__ amp, const float* __restrict__ att,
        const float* __restrict__ wtg, int total) {
    __shared__ float wt_lds[WT_LEN * N_WT];  // transposed [i][c], 40 KB
    for (int e = threadIdx.x; e < WT_LEN * N_WT; e += blockDim.x) {
        int c = e / WT_LEN;
        int i = e - c * WT_LEN;
        float v = wtg[e];
        if (c >= 4) v = tanhf(v);
        wt_lds[i * N_WT + c] = v;
    }
    __syncthreads();

    int gid = blockIdx.x * blockDim.x + threadIdx.x;
    if (gid >= total) return;

    int row = gid >> 18;
    float S  = io[gid];
    float y  = S - X0[row];               // index = cumsum - increment[:, :1]

    // exact fmod(y, 512): *2^-9 exact, floor exact, fma residual exact
    float qf  = floorf(y * (1.0f / 512.0f));
    float idx = fmaf(-512.0f, qf, y);
    if (idx < 0.0f)    idx += 512.0f;     // defensive
    if (idx >= 512.0f) idx -= 512.0f;

    float fl0   = floorf(idx);
    float alpha = idx - fl0;              // exact
    int il = ((int)fl0) & (WT_LEN - 1);
    int ih = (il + (alpha > 0.0f ? 1 : 0)) & (WT_LEN - 1);  // ceil % 512

    const float4* lo4 = (const float4*)(&wt_lds[il * N_WT]);
    const float4* hi4 = (const float4*)(&wt_lds[ih * N_WT]);
    const float4* a4  = (const float4*)(att + (size_t)gid * N_WT);

    float acc = 0.0f;
#pragma unroll
    for (int v = 0; v < 5; ++v) {
        float4 lo = lo4[v];
        float4 hi = hi4[v];
        float4 at = a4[v];
        acc += at.x * (lo.x + alpha * (hi.x - lo.x));
        acc += at.y * (lo.y + alpha * (hi.y - lo.y));
        acc += at.z * (lo.z + alpha * (hi.z - lo.z));
        acc += at.w * (lo.w + alpha * (hi.w - lo.w));
    }
    io[gid] = acc * amp[gid];
}

// ---------------------------------------------------------------------------
extern "C" void kernel_launch(void* const* d_in, const int* in_sizes, int n_in,
                              void* d_out, int out_size, void* d_ws, size_t ws_size,
                              hipStream_t stream) {
    const float* pitch = (const float*)d_in[0];
    const float* amp   = (const float*)d_in[1];
    const float* att   = (const float*)d_in[2];
    const float* wtg   = (const float*)d_in[3];
    float* S = (float*)d_out;            // scan staged in d_out, mixed in place

    float* A13 = (float*)d_ws;           // [512]
    float* S13 = A13 + NCH;              // [512]
    float* X0  = S13 + NCH;              // [16]
    float* INC = A13 + 4096;             // [TOTAL] if it fits
    const bool use_inc =
        ws_size >= (size_t)(4096 + TOTAL) * sizeof(float);

    if (use_inc) {
        up_kernel<true><<<NCH, DTHREADS, 0, stream>>>(pitch, A13, INC);
        mid_kernel<<<1, 64, 0, stream>>>(A13, pitch, S13, X0);
        down_kernel<true><<<NCH, DTHREADS, 0, stream>>>(INC, S13, S);
    } else {
        up_kernel<false><<<NCH, DTHREADS, 0, stream>>>(pitch, A13, nullptr);
        mid_kernel<<<1, 64, 0, stream>>>(A13, pitch, S13, X0);
        down_kernel<false><<<NCH, DTHREADS, 0, stream>>>(pitch, S13, S);
    }
    mix_kernel<<<(TOTAL + 255) / 256, 256, 0, stream>>>(S, X0, amp, att, wtg,
                                                        TOTAL);
}

// Round 4
// 501.319 us; speedup vs baseline: 1.1271x; 1.1271x over previous
//
#include <hip/hip_runtime.h>
#include <math.h>

#define WT_LEN 512
#define N_WT 20
#define B_ 16
#define T_ 262144           // 2^18 per row
#define TOTAL (B_ * T_)     // 4194304
#define CHUNK 8192          // 2^13 elems per block
#define NCHR 32             // chunks per row
#define NCH  512            // total chunks

// inc = (pitch / 44100) * 512 ; f32 division correctly rounded (verified R1/R2).
__device__ __forceinline__ float to_inc1(float x) {
    return (x / 44100.0f) * 512.0f;
}
__device__ __forceinline__ float4 to_inc4(float4 p) {
    float4 r;
    r.x = to_inc1(p.x); r.y = to_inc1(p.y);
    r.z = to_inc1(p.z); r.w = to_inc1(p.w);
    return r;
}

// ---------------------------------------------------------------------------
// U: per-chunk exact adjacent-pair tree reduction -> A13[chunk].
// Thread t handles 8 consecutive elems (in-register levels 1..3), then LDS
// slices for levels 4..13. Bit-exact adjacent-pair structure at every level.
// ---------------------------------------------------------------------------
__global__ __launch_bounds__(1024) void up_kernel(
        const float* __restrict__ pitch, float* __restrict__ A13) {
    __shared__ float red[2048];
    const int t = threadIdx.x;
    const size_t g0 = (size_t)blockIdx.x * CHUNK;

    const float4* p4 = (const float4*)(pitch + g0);
    float4 v0 = to_inc4(p4[2 * t]);
    float4 v1 = to_inc4(p4[2 * t + 1]);
    float t0 = v0.x + v0.y, t1 = v0.z + v0.w;
    float t2 = v1.x + v1.y, t3 = v1.z + v1.w;
    red[t] = (t0 + t1) + (t2 + t3);        // A3[t]
    __syncthreads();
    int off_prev = 0, off = 1024;
    for (int sz = 512; sz >= 1; sz >>= 1) {   // levels 4..13
        if (t < sz) red[off + t] = red[off_prev + 2 * t] + red[off_prev + 2 * t + 1];
        __syncthreads();
        off_prev = off; off += sz;
    }
    if (t == 0) A13[blockIdx.x] = red[2046];
}

// ---------------------------------------------------------------------------
// M: (a) lanes 0..15: exact odd-even scan of each row's 32 chunk totals ->
// S13, plus per-row x0. (b) all 1024 threads: build tanh'd transposed
// wavetable WTT[i*20+c] once, so mix never touches tanhf.
// ---------------------------------------------------------------------------
__global__ __launch_bounds__(1024) void mid_kernel(
        const float* __restrict__ A13, const float* __restrict__ pitch,
        const float* __restrict__ wtg, float* __restrict__ S13,
        float* __restrict__ X0, float* __restrict__ WTT) {
    int r = threadIdx.x;
    if (r < B_) {
        float l0[32], l1[16], l2[8], l3[4], l4[2], l5;
        for (int i = 0; i < 32; ++i) l0[i] = A13[r * 32 + i];
        for (int i = 0; i < 16; ++i) l1[i] = l0[2 * i] + l0[2 * i + 1];
        for (int i = 0; i < 8;  ++i) l2[i] = l1[2 * i] + l1[2 * i + 1];
        for (int i = 0; i < 4;  ++i) l3[i] = l2[2 * i] + l2[2 * i + 1];
        for (int i = 0; i < 2;  ++i) l4[i] = l3[2 * i] + l3[2 * i + 1];
        l5 = l4[0] + l4[1];

        float s4[2], s3[4], s2[8], s1[16], s0[32];
        s4[0] = l4[0]; s4[1] = l5;
        s3[0] = l3[0];
        for (int i = 0; i < 2; ++i) {
            s3[2 * i + 1] = s4[i];
            if (2 * i + 2 < 4) s3[2 * i + 2] = s4[i] + l3[2 * i + 2];
        }
        s2[0] = l2[0];
        for (int i = 0; i < 4; ++i) {
            s2[2 * i + 1] = s3[i];
            if (2 * i + 2 < 8) s2[2 * i + 2] = s3[i] + l2[2 * i + 2];
        }
        s1[0] = l1[0];
        for (int i = 0; i < 8; ++i) {
            s1[2 * i + 1] = s2[i];
            if (2 * i + 2 < 16) s1[2 * i + 2] = s2[i] + l1[2 * i + 2];
        }
        s0[0] = l0[0];
        for (int i = 0; i < 16; ++i) {
            s0[2 * i + 1] = s1[i];
            if (2 * i + 2 < 32) s0[2 * i + 2] = s1[i] + l0[2 * i + 2];
        }
        for (int i = 0; i < 32; ++i) S13[r * 32 + i] = s0[i];
        X0[r] = to_inc1(pitch[(size_t)r * T_]);
    }
    // wavetable prep: transpose + tanh once
    for (int e = threadIdx.x; e < WT_LEN * N_WT; e += 1024) {
        int c = e / WT_LEN;
        int i = e - c * WT_LEN;
        float v = wtg[e];
        if (c >= 4) v = tanhf(v);
        WTT[i * N_WT + c] = v;
    }
}

// ---------------------------------------------------------------------------
// D v2: register tree for levels 0..3 (8 elems/thread), LDS sweep only for
// levels 3..12 (8 KB). Seeds: P = S13[c-1] (chunk prefix, ==S_k[local -1] at
// every level by the odd-copy chain), s12[1] = S13[c]. Per-thread downsweep
// formulas reproduce the reference recursion add-for-add:
//   S[8t]=S3prev+x0  S[8t+1]=S3prev+t0  S[8t+2]=(S3prev+t0)+x2
//   S[8t+3]=S3prev+u0  S[8t+4]=(S3prev+u0)+x4  S[8t+5]=(S3prev+u0)+t2
//   S[8t+6]=((S3prev+u0)+t2)+x6  S[8t+7]=s3[t]      (S3prev=s3[t-1] or P)
// ---------------------------------------------------------------------------
__global__ __launch_bounds__(1024) void down_kernel(
        const float* __restrict__ pitch, const float* __restrict__ S13,
        float* __restrict__ sout) {
    __shared__ float a[2048];       // levels 3..13: 1024+512+...+1 = 2047
    const int t = threadIdx.x;
    const int c = blockIdx.x;
    const size_t g0 = (size_t)c * CHUNK;

    const float4* p4 = (const float4*)(pitch + g0);
    float4 va = to_inc4(p4[2 * t]);
    float4 vb = to_inc4(p4[2 * t + 1]);
    float x0 = va.x, x2 = va.z, x4 = vb.x, x6 = vb.z;
    float t0 = va.x + va.y, t1 = va.z + va.w;
    float t2 = vb.x + vb.y, t3 = vb.z + vb.w;
    float u0 = t0 + t1, u1 = t2 + t3;
    a[t] = u0 + u1;                 // A3[t]
    __syncthreads();

    // up-sweep levels 4..12 (offsets 1024,1536,1792,1920,1984,2016,2032,2040,2044)
    int bp = 0, b = 1024;
    for (int sz = 512; sz >= 2; sz >>= 1) {
        if (t < sz) a[b + t] = a[bp + 2 * t] + a[bp + 2 * t + 1];
        __syncthreads();
        bp = b; b += sz;
    }

    const float P   = (c & (NCHR - 1)) ? S13[c - 1] : 0.0f;
    const float T13 = S13[c];
    if (t == 0) {
        a[2044] = P + a[2044];      // s12[0] = P + A12[0]
        a[2045] = T13;              // s12[1] = S13[c]
    }
    __syncthreads();

    // down-sweep levels 11..3, in place per slice
    const int offk[10] = {0, 1024, 1536, 1792, 1920, 1984, 2016, 2032, 2040, 2044};
    for (int k = 11; k >= 3; --k) {
        int m = 1 << (13 - k), half = m >> 1;
        int bk = offk[k - 3], bn = offk[k - 2];
        if (t < half) {
            float sn = a[bn + t];                  // s_{k+1}[t], finalized
            int j = 2 * t + 2;
            float av = (j < m) ? a[bk + j] : 0.0f; // raw A_k (same-thread slot)
            a[bk + 2 * t + 1] = sn;
            if (j < m) a[bk + j] = sn + av;
        }
        if (t == 0) a[bk] = P + a[bk];             // s_k[0]
        __syncthreads();
    }

    float S3prev = t ? a[t - 1] : P;
    float s3t = a[t];
    float s1a = S3prev + t0;        // s1[4t]
    float s2a = S3prev + u0;        // s2[2t]
    float s1c = s2a + t2;           // s1[4t+2]
    (void)t1; (void)t3; (void)u1;

    float4* q4 = (float4*)(sout + g0);
    q4[2 * t]     = make_float4(S3prev + x0, s1a, s1a + x2, s2a);
    q4[2 * t + 1] = make_float4(s2a + x4, s1c, s1c + x6, s3t);
}

// ---------------------------------------------------------------------------
// mix v2: persistent blocks, wavetable loaded ONCE per block from WTT
// (already tanh'd + transposed). 512 thr + 40 KB LDS -> 4 blocks/CU (100%).
// ---------------------------------------------------------------------------
__global__ __launch_bounds__(512) void mix_kernel(
        float* io, const float* __restrict__ X0,
        const float* __restrict__ amp, const float* __restrict__ att,
        const float* __restrict__ WTT, int ntiles) {
    __shared__ float wt_lds[WT_LEN * N_WT];   // [i][c], 40 KB
    {
        const float4* src = (const float4*)WTT;
        float4* dst = (float4*)wt_lds;
#pragma unroll
        for (int r = 0; r < 5; ++r)
            dst[threadIdx.x + 512 * r] = src[threadIdx.x + 512 * r];
    }
    __syncthreads();

    for (int tile = blockIdx.x; tile < ntiles; tile += gridDim.x) {
        int gid = tile * 512 + threadIdx.x;
        int row = gid >> 18;
        float S = io[gid];
        float y = S - X0[row];            // index = cumsum - increment[:, :1]

        // exact fmod(y, 512)
        float qf  = floorf(y * (1.0f / 512.0f));
        float idx = fmaf(-512.0f, qf, y);
        if (idx < 0.0f)    idx += 512.0f;
        if (idx >= 512.0f) idx -= 512.0f;

        float fl0   = floorf(idx);
        float alpha = idx - fl0;
        int il = ((int)fl0) & (WT_LEN - 1);
        int ih = (il + (alpha > 0.0f ? 1 : 0)) & (WT_LEN - 1);

        const float4* lo4 = (const float4*)(&wt_lds[il * N_WT]);
        const float4* hi4 = (const float4*)(&wt_lds[ih * N_WT]);
        const float4* a4  = (const float4*)(att + (size_t)gid * N_WT);

        float acc = 0.0f;
#pragma unroll
        for (int v = 0; v < 5; ++v) {
            float4 lo = lo4[v];
            float4 hi = hi4[v];
            float4 at = a4[v];
            acc += at.x * (lo.x + alpha * (hi.x - lo.x));
            acc += at.y * (lo.y + alpha * (hi.y - lo.y));
            acc += at.z * (lo.z + alpha * (hi.z - lo.z));
            acc += at.w * (lo.w + alpha * (hi.w - lo.w));
        }
        io[gid] = acc * amp[gid];
    }
}

// ---------------------------------------------------------------------------
extern "C" void kernel_launch(void* const* d_in, const int* in_sizes, int n_in,
                              void* d_out, int out_size, void* d_ws, size_t ws_size,
                              hipStream_t stream) {
    const float* pitch = (const float*)d_in[0];
    const float* amp   = (const float*)d_in[1];
    const float* att   = (const float*)d_in[2];
    const float* wtg   = (const float*)d_in[3];
    float* S = (float*)d_out;           // scan staged in d_out, mixed in place

    float* A13 = (float*)d_ws;          // [512]
    float* S13 = A13 + NCH;             // [512]
    float* X0  = S13 + NCH;             // [16]
    float* WTT = X0 + 64;               // [10240] (16-float aligned)

    up_kernel<<<NCH, 1024, 0, stream>>>(pitch, A13);
    mid_kernel<<<1, 1024, 0, stream>>>(A13, pitch, wtg, S13, X0, WTT);
    down_kernel<<<NCH, 1024, 0, stream>>>(pitch, S13, S);
    mix_kernel<<<1024, 512, 0, stream>>>(S, X0, amp, att, WTT,
                                         TOTAL / 512);
}